// Round 12
// baseline (460.096 us; speedup 1.0000x reference)
//
#include <hip/hip_runtime.h>

#define NN 100000
#define NE 1600000
#define NG 1024
#define NODE_IN 163
#define SLOPE 0.01f
#define NBUK 391      // ceil(100000/256)
#define BUKSH 8       // 256 nodes per bucket
#define EPB 8192      // edges per partition block
#define NBLK ((NE + EPB - 1) / EPB)   // 196

// ---------------- CSR build (privatized counting sort; round-4, verified) -------------
__global__ void k_hist(const int* __restrict__ dst, int* __restrict__ bh, int E) {
  __shared__ int h[NBUK];
  for (int i = threadIdx.x; i < NBUK; i += 256) h[i] = 0;
  __syncthreads();
  int beg = blockIdx.x * EPB, end = min(E, beg + EPB);
  for (int e = beg + threadIdx.x; e < end; e += 256) atomicAdd(&h[dst[e] >> BUKSH], 1);
  __syncthreads();
  for (int i = threadIdx.x; i < NBUK; i += 256) bh[blockIdx.x * NBUK + i] = h[i];
}

__global__ void k_bucket_scan(int* __restrict__ bh, int* __restrict__ btot) {
  __shared__ int s[256];
  int bucket = blockIdx.x, tid = threadIdx.x;
  int v = (tid < NBLK) ? bh[tid * NBUK + bucket] : 0;
  s[tid] = v;
  __syncthreads();
  for (int off = 1; off < 256; off <<= 1) {
    int t = (tid >= off) ? s[tid - off] : 0;
    __syncthreads();
    s[tid] += t;
    __syncthreads();
  }
  if (tid < NBLK) bh[tid * NBUK + bucket] = s[tid] - v;
  if (tid == 255) btot[bucket] = s[255];
}

__global__ void k_btot_scan(const int* __restrict__ btot, int* __restrict__ boffs, int E) {
  __shared__ int s[512];
  int tid = threadIdx.x;
  int v = (tid < NBUK) ? btot[tid] : 0;
  s[tid] = v;
  __syncthreads();
  for (int off = 1; off < 512; off <<= 1) {
    int t = (tid >= off) ? s[tid - off] : 0;
    __syncthreads();
    s[tid] += t;
    __syncthreads();
  }
  if (tid < NBUK) boffs[tid] = s[tid] - v;
  if (tid == 0) boffs[NBUK] = E;
}

__global__ void k_scatter(const int* __restrict__ src, const int* __restrict__ dst,
                          const int* __restrict__ bh, const int* __restrict__ boffs,
                          unsigned* __restrict__ bedge, int E) {
  __shared__ int cur[NBUK];
  for (int i = threadIdx.x; i < NBUK; i += 256)
    cur[i] = boffs[i] + bh[blockIdx.x * NBUK + i];
  __syncthreads();
  int beg = blockIdx.x * EPB, end = min(E, beg + EPB);
  for (int e = beg + threadIdx.x; e < end; e += 256) {
    int d = dst[e];
    int pos = atomicAdd(&cur[d >> BUKSH], 1);
    bedge[pos] = (unsigned)src[e] | ((unsigned)(d & 255) << 17);
  }
}

__global__ void k_b2csr(const unsigned* __restrict__ bedge, const int* __restrict__ boffs,
                        int* __restrict__ offs, float* __restrict__ dis,
                        int* __restrict__ csr, int N) {
  __shared__ int lcnt[256];
  __shared__ int s[256];
  __shared__ int lcur[256];
  int b = blockIdx.x, tid = threadIdx.x;
  int beg = boffs[b], end = boffs[b + 1];
  lcnt[tid] = 0;
  __syncthreads();
  for (int e = beg + tid; e < end; e += 256) atomicAdd(&lcnt[bedge[e] >> 17], 1);
  __syncthreads();
  int v = lcnt[tid];
  s[tid] = v;
  __syncthreads();
  for (int off = 1; off < 256; off <<= 1) {
    int t = (tid >= off) ? s[tid - off] : 0;
    __syncthreads();
    s[tid] += t;
    __syncthreads();
  }
  int o = s[tid] - v;
  int node = (b << BUKSH) + tid;
  if (node <= N) offs[node] = beg + o;
  if (node < N) dis[node] = rsqrtf((float)(v + 1));
  lcur[tid] = o;
  __syncthreads();
  for (int e = beg + tid; e < end; e += 256) {
    unsigned w = bedge[e];
    int p = atomicAdd(&lcur[w >> 17], 1);
    csr[beg + p] = (int)(w & 0x1FFFFu);
  }
}

// ---------------- GEMM: 64-row tile, 4x4 microtile, BK=32, k-major X in LDS -----------
// Lane: 4 rows (r0..r0+3) x 4 cols (c0..c0+3); acc = 16 regs. Demand ~70-90 VGPR ->
// under the 128 cliff hint-free (rounds 7/8/10: hints spill; round 9/11: 32-acc = 132
// VGPR -> 3 waves/SIMD, latency-bound at VALUBusy 20%). unroll-8 bounds pipelining.
// xa read = 4-addr broadcast; wr = 2-way alias; sX pitch 66 -> staging writes 2-way.
template<int K>
__launch_bounds__(256)
__global__ void k_gemm(const float* __restrict__ X, const float* __restrict__ W,
                       const float* __restrict__ disv, float* __restrict__ Y, int N) {
  constexpr int BK = 32;
  constexpr int KC = (K + BK - 1) / BK;   // 163->6, 64->2
  constexpr int XP = 66;                  // sX pitch (66 = 2 mod 32 -> 2-way writes)
  __shared__ float sX[2][BK * XP];
  __shared__ float sW[2][BK * 64];
  const int tid = threadIdx.x;
  const int lane = tid & 63, wv = tid >> 6;
  const int r0 = wv * 16 + ((lane >> 4) << 2);    // 4 rows within 64-row tile
  const int c0 = (lane & 15) << 2;                // 4 cols
  const int gbase = blockIdx.x << 6;
  const int srow = tid >> 2, koff = (tid & 3) << 3;  // X staging: row, k-offset(0/8/16/24)
  const int wk = tid >> 4, wc4 = (tid & 15) << 2;    // W staging: k, col

  int gr = gbase + srow;
  if (K == NODE_IN) gr = (gr < N) ? gr : (N - 1);   // input X is exact-sized
  const float* xr = X + (size_t)gr * K + koff;      // K==64: workspace has NPAD rows

  float4 rx0, rx1, rw0, rw1;

  auto loadX = [&](int c) {
    if (K == NODE_IN && c == KC - 1) {   // k = 160 + koff + j; only koff==0, j<3 valid
      rx1 = make_float4(0.f, 0.f, 0.f, 0.f);
      if (koff == 0) rx0 = make_float4(xr[160], xr[161], xr[162], 0.f);
      else           rx0 = make_float4(0.f, 0.f, 0.f, 0.f);
    } else {
      rx0 = *(const float4*)(xr + c * BK);
      rx1 = *(const float4*)(xr + c * BK + 4);
    }
  };
  auto loadW = [&](int c) {
    int gk0 = c * BK + wk, gk1 = c * BK + 16 + wk;
    if (K % BK == 0) {
      rw0 = *(const float4*)(W + (size_t)gk0 * 64 + wc4);
      rw1 = *(const float4*)(W + (size_t)gk1 * 64 + wc4);
    } else {
      rw0 = (gk0 < K) ? *(const float4*)(W + (size_t)gk0 * 64 + wc4)
                      : make_float4(0.f, 0.f, 0.f, 0.f);
      rw1 = (gk1 < K) ? *(const float4*)(W + (size_t)gk1 * 64 + wc4)
                      : make_float4(0.f, 0.f, 0.f, 0.f);
    }
  };
  auto writeLDS = [&](int b) {
    float* xb = sX[b];
    xb[(koff + 0) * XP + srow] = rx0.x;
    xb[(koff + 1) * XP + srow] = rx0.y;
    xb[(koff + 2) * XP + srow] = rx0.z;
    xb[(koff + 3) * XP + srow] = rx0.w;
    xb[(koff + 4) * XP + srow] = rx1.x;
    xb[(koff + 5) * XP + srow] = rx1.y;
    xb[(koff + 6) * XP + srow] = rx1.z;
    xb[(koff + 7) * XP + srow] = rx1.w;
    float* wb = sW[b];
    *(float4*)(wb + wk * 64 + wc4) = rw0;
    *(float4*)(wb + (16 + wk) * 64 + wc4) = rw1;
  };

  loadX(0); loadW(0); writeLDS(0);

  float acc[16];
  #pragma unroll
  for (int i = 0; i < 16; ++i) acc[i] = 0.f;

  #pragma unroll 1
  for (int c = 0; c < KC; ++c) {
    if (c + 1 < KC) { loadX(c + 1); loadW(c + 1); }   // issue early (T14)
    __syncthreads();
    const float* sXc = sX[c & 1];
    const float* sWc = sW[c & 1];
    #pragma unroll 8
    for (int k = 0; k < BK; ++k) {
      float4 xa = *(const float4*)(sXc + k * XP + r0);   // 4-addr broadcast
      float4 wr = *(const float4*)(sWc + k * 64 + c0);   // 2-way alias
      acc[0]  += xa.x * wr.x; acc[1]  += xa.x * wr.y;
      acc[2]  += xa.x * wr.z; acc[3]  += xa.x * wr.w;
      acc[4]  += xa.y * wr.x; acc[5]  += xa.y * wr.y;
      acc[6]  += xa.y * wr.z; acc[7]  += xa.y * wr.w;
      acc[8]  += xa.z * wr.x; acc[9]  += xa.z * wr.y;
      acc[10] += xa.z * wr.z; acc[11] += xa.z * wr.w;
      acc[12] += xa.w * wr.x; acc[13] += xa.w * wr.y;
      acc[14] += xa.w * wr.z; acc[15] += xa.w * wr.w;
    }
    if (c + 1 < KC) writeLDS((c + 1) & 1);            // write late (other buffer)
  }

  #pragma unroll
  for (int r = 0; r < 4; ++r) {
    int row = gbase + r0 + r;
    if (row < N) {
      float d = disv[row];
      *(float4*)(Y + (size_t)row * 64 + c0) =
          make_float4(acc[r*4+0]*d, acc[r*4+1]*d, acc[r*4+2]*d, acc[r*4+3]*d);
    }
  }
}

// One wave per node: Hout[i] = lrelu( (Hps[i] + sum_{e->i} Hps[src]) * dis[i] + b )
__launch_bounds__(256)
__global__ void k_agg(const float* __restrict__ Hps, const int* __restrict__ offs,
                      const int* __restrict__ csr, const float* __restrict__ dis,
                      const float* __restrict__ bias, float* __restrict__ Hout, int N) {
  int node = blockIdx.x * 4 + (threadIdx.x >> 6);
  if (node >= N) return;
  int lane = threadIdx.x & 63;
  int beg = offs[node], end = offs[node + 1];
  float acc = Hps[(size_t)node * 64 + lane];
  int e = beg;
  for (; e + 8 <= end; e += 8) {
    int s0 = csr[e + 0], s1 = csr[e + 1], s2 = csr[e + 2], s3 = csr[e + 3];
    int s4 = csr[e + 4], s5 = csr[e + 5], s6 = csr[e + 6], s7 = csr[e + 7];
    acc += Hps[(size_t)s0 * 64 + lane];
    acc += Hps[(size_t)s1 * 64 + lane];
    acc += Hps[(size_t)s2 * 64 + lane];
    acc += Hps[(size_t)s3 * 64 + lane];
    acc += Hps[(size_t)s4 * 64 + lane];
    acc += Hps[(size_t)s5 * 64 + lane];
    acc += Hps[(size_t)s6 * 64 + lane];
    acc += Hps[(size_t)s7 * 64 + lane];
  }
  for (; e + 4 <= end; e += 4) {
    int s0 = csr[e], s1 = csr[e + 1], s2 = csr[e + 2], s3 = csr[e + 3];
    acc += Hps[(size_t)s0 * 64 + lane];
    acc += Hps[(size_t)s1 * 64 + lane];
    acc += Hps[(size_t)s2 * 64 + lane];
    acc += Hps[(size_t)s3 * 64 + lane];
  }
  for (; e < end; ++e) acc += Hps[(size_t)csr[e] * 64 + lane];
  acc = acc * dis[node] + bias[lane];
  Hout[(size_t)node * 64 + lane] = (acc > 0.f) ? acc : SLOPE * acc;
}

// One wave per graph: mean-pool + fc1 + lrelu + fc2
__launch_bounds__(64)
__global__ void k_pool(const float* __restrict__ H, const int* __restrict__ batch,
                       const float* __restrict__ f1W, const float* __restrict__ f1b,
                       const float* __restrict__ f2W, const float* __restrict__ f2b,
                       float* __restrict__ out, int N) {
  int g = blockIdx.x;
  int lane = threadIdx.x;
  int lo = 0, hi = N;
  while (lo < hi) { int m = (lo + hi) >> 1; if (batch[m] < g) lo = m + 1; else hi = m; }
  int beg = lo;
  hi = N;
  while (lo < hi) { int m = (lo + hi) >> 1; if (batch[m] < g + 1) lo = m + 1; else hi = m; }
  int end = lo;
  float acc = 0.f;
  for (int r = beg; r < end; ++r) acc += H[(size_t)r * 64 + lane];
  float c = (float)(end - beg);
  acc /= (c < 1.f ? 1.f : c);
  __shared__ float p[64];
  p[lane] = acc;
  __syncthreads();
  float q = f1b[lane];
  #pragma unroll
  for (int k = 0; k < 64; ++k) q += p[k] * f1W[k * 64 + lane];
  q = (q > 0.f) ? q : SLOPE * q;
  float v = q * f2W[lane];
  #pragma unroll
  for (int off = 32; off > 0; off >>= 1) v += __shfl_down(v, off, 64);
  if (lane == 0) out[g] = v + f2b[0];
}

extern "C" void kernel_launch(void* const* d_in, const int* in_sizes, int n_in,
                              void* d_out, int out_size, void* d_ws, size_t ws_size,
                              hipStream_t stream) {
  const float* x    = (const float*)d_in[0];
  const int*  eidx  = (const int*)d_in[1];
  const int*  batch = (const int*)d_in[2];
  const float* W0 = (const float*)d_in[3];
  const float* b0 = (const float*)d_in[4];
  const float* W1 = (const float*)d_in[5];
  const float* b1 = (const float*)d_in[6];
  const float* W2 = (const float*)d_in[7];
  const float* b2 = (const float*)d_in[8];
  const float* f1W = (const float*)d_in[9];
  const float* f1b = (const float*)d_in[10];
  const float* f2W = (const float*)d_in[11];
  const float* f2b = (const float*)d_in[12];
  float* out = (float*)d_out;

  const int N = NN, E = NE;
  const int* src  = eidx;
  const int* dstp = eidx + E;

  const size_t NPAD = 100096;
  char* w = (char*)d_ws;
  float* bufA  = (float*)w; w += NPAD * 64 * 4;   // bedge aliases bufA (dead until gemm0)
  float* bufB  = (float*)w; w += NPAD * 64 * 4;
  int*   csr   = (int*)w;   w += (size_t)E * 4;
  int*   offs  = (int*)w;   w += (size_t)(N + 4) * 4;
  float* dis   = (float*)w; w += (size_t)N * 4;
  int*   bh    = (int*)w;   w += (size_t)NBLK * NBUK * 4;
  int*   btot  = (int*)w;   w += (NBUK + 1) * 4;
  int*   boffs = (int*)w;   w += (NBUK + 1) * 4;
  unsigned* bedge = (unsigned*)bufA;

  k_hist<<<NBLK, 256, 0, stream>>>(dstp, bh, E);
  k_bucket_scan<<<NBUK, 256, 0, stream>>>(bh, btot);
  k_btot_scan<<<1, 512, 0, stream>>>(btot, boffs, E);
  k_scatter<<<NBLK, 256, 0, stream>>>(src, dstp, bh, boffs, bedge, E);
  k_b2csr<<<NBUK, 256, 0, stream>>>(bedge, boffs, offs, dis, csr, N);

  const int NTB = (N + 63) / 64;   // 1563
  k_gemm<NODE_IN><<<NTB, 256, 0, stream>>>(x, W0, dis, bufA, N);
  k_agg<<<(N + 3) / 4, 256, 0, stream>>>(bufA, offs, csr, dis, b0, bufB, N);
  k_gemm<64><<<NTB, 256, 0, stream>>>(bufB, W1, dis, bufA, N);
  k_agg<<<(N + 3) / 4, 256, 0, stream>>>(bufA, offs, csr, dis, b1, bufB, N);
  k_gemm<64><<<NTB, 256, 0, stream>>>(bufB, W2, dis, bufA, N);
  k_agg<<<(N + 3) / 4, 256, 0, stream>>>(bufA, offs, csr, dis, b2, bufB, N);
  k_pool<<<NG, 64, 0, stream>>>(bufB, batch, f1W, f1b, f2W, f2b, out, N);
}

// Round 13
// 351.256 us; speedup vs baseline: 1.3099x; 1.3099x over previous
//
#include <hip/hip_runtime.h>

#define NN 100000
#define NE 1600000
#define NG 1024
#define NODE_IN 163
#define SLOPE 0.01f
#define NBUK 391
#define BUKSH 8
#define EPB 8192
#define NBLK ((NE + EPB - 1) / EPB)

typedef short s16x8 __attribute__((ext_vector_type(8)));
typedef float f32x4 __attribute__((ext_vector_type(4)));

__device__ __forceinline__ unsigned short bf16_rne(float x) {
  unsigned u = __float_as_uint(x);
  return (unsigned short)((u + 0x7FFFu + ((u >> 16) & 1u)) >> 16);
}
__device__ __forceinline__ float bf16_f32(unsigned short h) {
  return __uint_as_float(((unsigned)h) << 16);
}

// ---------------- CSR build (privatized counting sort; round-4, verified) -------------
__global__ void k_hist(const int* __restrict__ dst, int* __restrict__ bh, int E) {
  __shared__ int h[NBUK];
  for (int i = threadIdx.x; i < NBUK; i += 256) h[i] = 0;
  __syncthreads();
  int beg = blockIdx.x * EPB, end = min(E, beg + EPB);
  for (int e = beg + threadIdx.x; e < end; e += 256) atomicAdd(&h[dst[e] >> BUKSH], 1);
  __syncthreads();
  for (int i = threadIdx.x; i < NBUK; i += 256) bh[blockIdx.x * NBUK + i] = h[i];
}

__global__ void k_bucket_scan(int* __restrict__ bh, int* __restrict__ btot) {
  __shared__ int s[256];
  int bucket = blockIdx.x, tid = threadIdx.x;
  int v = (tid < NBLK) ? bh[tid * NBUK + bucket] : 0;
  s[tid] = v;
  __syncthreads();
  for (int off = 1; off < 256; off <<= 1) {
    int t = (tid >= off) ? s[tid - off] : 0;
    __syncthreads();
    s[tid] += t;
    __syncthreads();
  }
  if (tid < NBLK) bh[tid * NBUK + bucket] = s[tid] - v;
  if (tid == 255) btot[bucket] = s[255];
}

__global__ void k_btot_scan(const int* __restrict__ btot, int* __restrict__ boffs, int E) {
  __shared__ int s[512];
  int tid = threadIdx.x;
  int v = (tid < NBUK) ? btot[tid] : 0;
  s[tid] = v;
  __syncthreads();
  for (int off = 1; off < 512; off <<= 1) {
    int t = (tid >= off) ? s[tid - off] : 0;
    __syncthreads();
    s[tid] += t;
    __syncthreads();
  }
  if (tid < NBUK) boffs[tid] = s[tid] - v;
  if (tid == 0) boffs[NBUK] = E;
}

__global__ void k_scatter(const int* __restrict__ src, const int* __restrict__ dst,
                          const int* __restrict__ bh, const int* __restrict__ boffs,
                          unsigned* __restrict__ bedge, int E) {
  __shared__ int cur[NBUK];
  for (int i = threadIdx.x; i < NBUK; i += 256)
    cur[i] = boffs[i] + bh[blockIdx.x * NBUK + i];
  __syncthreads();
  int beg = blockIdx.x * EPB, end = min(E, beg + EPB);
  for (int e = beg + threadIdx.x; e < end; e += 256) {
    int d = dst[e];
    int pos = atomicAdd(&cur[d >> BUKSH], 1);
    bedge[pos] = (unsigned)src[e] | ((unsigned)(d & 255) << 17);
  }
}

__global__ void k_b2csr(const unsigned* __restrict__ bedge, const int* __restrict__ boffs,
                        int* __restrict__ offs, float* __restrict__ dis,
                        int* __restrict__ csr, int N) {
  __shared__ int lcnt[256];
  __shared__ int s[256];
  __shared__ int lcur[256];
  int b = blockIdx.x, tid = threadIdx.x;
  int beg = boffs[b], end = boffs[b + 1];
  lcnt[tid] = 0;
  __syncthreads();
  for (int e = beg + tid; e < end; e += 256) atomicAdd(&lcnt[bedge[e] >> 17], 1);
  __syncthreads();
  int v = lcnt[tid];
  s[tid] = v;
  __syncthreads();
  for (int off = 1; off < 256; off <<= 1) {
    int t = (tid >= off) ? s[tid - off] : 0;
    __syncthreads();
    s[tid] += t;
    __syncthreads();
  }
  int o = s[tid] - v;
  int node = (b << BUKSH) + tid;
  if (node <= N) offs[node] = beg + o;
  if (node < N) dis[node] = rsqrtf((float)(v + 1));
  lcur[tid] = o;
  __syncthreads();
  for (int e = beg + tid; e < end; e += 256) {
    unsigned w = bedge[e];
    int p = atomicAdd(&lcur[w >> 17], 1);
    csr[beg + p] = (int)(w & 0x1FFFFu);
  }
}

// ---------------- W pre-split: W[K][64] fp32 -> Wt_hi/lo[64][KP] bf16 (transposed) ----
__global__ void k_wsplit(const float* __restrict__ W, short* __restrict__ hi,
                         short* __restrict__ lo, int K, int KP) {
  int idx = blockIdx.x * 256 + threadIdx.x;
  if (idx >= 64 * KP) return;
  int c = idx / KP, kk = idx - c * KP;
  float v = (kk < K) ? W[(size_t)kk * 64 + c] : 0.f;
  unsigned short h = bf16_rne(v);
  hi[idx] = (short)h;
  lo[idx] = (short)bf16_rne(v - bf16_f32(h));
}

// ---------------- GEMM via MFMA split-bf16: Y = (Xhi+Xlo)@Whi + Xhi@Wlo, *dis --------
// Block: 128 rows x 64 cols, 4 waves; wave = 32 rows (2 row-tiles) x 4 col-tiles.
// mfma_f32_16x16x32_bf16; C/D: col=lane&15, row=(lane>>4)*4+reg (verified layout).
// A/B frags: 16-dim = lane&15, k = (lane>>4)*8 + j (symmetric -> k-perm cancels).
// LDS 60KB (2 blk/CU). No occupancy hints (hinted builds spilled, rounds 7/8/10).
template<int K, int KP>
__launch_bounds__(256)
__global__ void k_gemm(const float* __restrict__ X, const short* __restrict__ Whi,
                       const short* __restrict__ Wlo, const float* __restrict__ disv,
                       float* __restrict__ Y, int N) {
  constexpr int KC = KP / 32;
  constexpr int PA = 40;   // shorts per 32-k row slice (+8 pad): 80B, 16B-aligned
  constexpr int PB = 40;
  __shared__ __align__(16) short sAh[2][128 * PA];
  __shared__ __align__(16) short sAl[2][128 * PA];
  __shared__ __align__(16) short sBh[2][64 * PB];
  __shared__ __align__(16) short sBl[2][64 * PB];

  const int tid = threadIdx.x;
  const int lane = tid & 63, wv = tid >> 6;
  const int l15 = lane & 15, l4 = lane >> 4;
  const int gbase = blockIdx.x << 7;

  const int arow = tid >> 1, akh = (tid & 1) << 4;   // A staging: row, k-half
  int grow = gbase + arow;
  if (K != KP) grow = min(grow, N - 1);              // K=163: input exact-sized
  const float* xr = X + (size_t)grow * K;
  const int bcol = tid >> 2, bk8 = (tid & 3) << 3;   // B staging: col, k-octet

  float4 ra0, ra1, ra2, ra3;
  s16x8 rbh, rbl;

  auto loadA = [&](int c) {
    if (K != KP && c == KC - 1) {                    // tail chunk kb=160: k 160..162
      ra0 = ra1 = ra2 = ra3 = make_float4(0.f, 0.f, 0.f, 0.f);
      if (akh == 0) { ra0.x = xr[160]; ra0.y = xr[161]; ra0.z = xr[162]; }
    } else {
      const float* p = xr + c * 32 + akh;
      ra0 = *(const float4*)(p);
      ra1 = *(const float4*)(p + 4);
      ra2 = *(const float4*)(p + 8);
      ra3 = *(const float4*)(p + 12);
    }
  };
  auto loadB = [&](int c) {
    const size_t o = (size_t)bcol * KP + c * 32 + bk8;
    rbh = *(const s16x8*)(Whi + o);
    rbl = *(const s16x8*)(Wlo + o);
  };
  auto writeLDS = [&](int b) {
    short hb[16], lb[16];
    float v[16] = {ra0.x, ra0.y, ra0.z, ra0.w, ra1.x, ra1.y, ra1.z, ra1.w,
                   ra2.x, ra2.y, ra2.z, ra2.w, ra3.x, ra3.y, ra3.z, ra3.w};
    #pragma unroll
    for (int j = 0; j < 16; ++j) {
      unsigned short h = bf16_rne(v[j]);
      hb[j] = (short)h;
      lb[j] = (short)bf16_rne(v[j] - bf16_f32(h));
    }
    short* ah = sAh[b] + arow * PA + akh;
    *(s16x8*)(ah) = *(const s16x8*)(hb);
    *(s16x8*)(ah + 8) = *(const s16x8*)(hb + 8);
    short* al = sAl[b] + arow * PA + akh;
    *(s16x8*)(al) = *(const s16x8*)(lb);
    *(s16x8*)(al + 8) = *(const s16x8*)(lb + 8);
    *(s16x8*)(sBh[b] + bcol * PB + bk8) = rbh;
    *(s16x8*)(sBl[b] + bcol * PB + bk8) = rbl;
  };

  f32x4 acc[2][4];
  #pragma unroll
  for (int rt = 0; rt < 2; ++rt)
    #pragma unroll
    for (int ct = 0; ct < 4; ++ct) acc[rt][ct] = (f32x4){0.f, 0.f, 0.f, 0.f};

  loadA(0); loadB(0); writeLDS(0);
  __syncthreads();

  #pragma unroll 1
  for (int c = 0; c < KC; ++c) {
    if (c + 1 < KC) { loadA(c + 1); loadB(c + 1); }   // issue early (T14)
    const int b = c & 1;
    const int aoff0 = (wv * 32 + l15) * PA + l4 * 8;
    const int aoff1 = aoff0 + 16 * PA;
    s16x8 a0h = *(const s16x8*)(sAh[b] + aoff0);
    s16x8 a0l = *(const s16x8*)(sAl[b] + aoff0);
    s16x8 a1h = *(const s16x8*)(sAh[b] + aoff1);
    s16x8 a1l = *(const s16x8*)(sAl[b] + aoff1);
    #pragma unroll
    for (int ct = 0; ct < 4; ++ct) {
      const int boff = (ct * 16 + l15) * PB + l4 * 8;
      s16x8 bh = *(const s16x8*)(sBh[b] + boff);
      s16x8 bl = *(const s16x8*)(sBl[b] + boff);
      acc[0][ct] = __builtin_amdgcn_mfma_f32_16x16x32_bf16(a0h, bh, acc[0][ct], 0, 0, 0);
      acc[0][ct] = __builtin_amdgcn_mfma_f32_16x16x32_bf16(a0l, bh, acc[0][ct], 0, 0, 0);
      acc[0][ct] = __builtin_amdgcn_mfma_f32_16x16x32_bf16(a0h, bl, acc[0][ct], 0, 0, 0);
      acc[1][ct] = __builtin_amdgcn_mfma_f32_16x16x32_bf16(a1h, bh, acc[1][ct], 0, 0, 0);
      acc[1][ct] = __builtin_amdgcn_mfma_f32_16x16x32_bf16(a1l, bh, acc[1][ct], 0, 0, 0);
      acc[1][ct] = __builtin_amdgcn_mfma_f32_16x16x32_bf16(a1h, bl, acc[1][ct], 0, 0, 0);
    }
    if (c + 1 < KC) { writeLDS((c + 1) & 1); __syncthreads(); }
  }

  const int rb = gbase + wv * 32;
  #pragma unroll
  for (int rt = 0; rt < 2; ++rt) {
    #pragma unroll
    for (int j = 0; j < 4; ++j) {
      int row = rb + rt * 16 + l4 * 4 + j;
      if (row < N) {
        float d = disv[row];
        float* yp = Y + (size_t)row * 64 + l15;
        yp[0]  = acc[rt][0][j] * d;
        yp[16] = acc[rt][1][j] * d;
        yp[32] = acc[rt][2][j] * d;
        yp[48] = acc[rt][3][j] * d;
      }
    }
  }
}

// One wave per node: Hout[i] = lrelu( (Hps[i] + sum_{e->i} Hps[src]) * dis[i] + b )
__launch_bounds__(256)
__global__ void k_agg(const float* __restrict__ Hps, const int* __restrict__ offs,
                      const int* __restrict__ csr, const float* __restrict__ dis,
                      const float* __restrict__ bias, float* __restrict__ Hout, int N) {
  int node = blockIdx.x * 4 + (threadIdx.x >> 6);
  if (node >= N) return;
  int lane = threadIdx.x & 63;
  int beg = offs[node], end = offs[node + 1];
  float acc = Hps[(size_t)node * 64 + lane];
  int e = beg;
  for (; e + 8 <= end; e += 8) {
    int s0 = csr[e + 0], s1 = csr[e + 1], s2 = csr[e + 2], s3 = csr[e + 3];
    int s4 = csr[e + 4], s5 = csr[e + 5], s6 = csr[e + 6], s7 = csr[e + 7];
    acc += Hps[(size_t)s0 * 64 + lane];
    acc += Hps[(size_t)s1 * 64 + lane];
    acc += Hps[(size_t)s2 * 64 + lane];
    acc += Hps[(size_t)s3 * 64 + lane];
    acc += Hps[(size_t)s4 * 64 + lane];
    acc += Hps[(size_t)s5 * 64 + lane];
    acc += Hps[(size_t)s6 * 64 + lane];
    acc += Hps[(size_t)s7 * 64 + lane];
  }
  for (; e + 4 <= end; e += 4) {
    int s0 = csr[e], s1 = csr[e + 1], s2 = csr[e + 2], s3 = csr[e + 3];
    acc += Hps[(size_t)s0 * 64 + lane];
    acc += Hps[(size_t)s1 * 64 + lane];
    acc += Hps[(size_t)s2 * 64 + lane];
    acc += Hps[(size_t)s3 * 64 + lane];
  }
  for (; e < end; ++e) acc += Hps[(size_t)csr[e] * 64 + lane];
  acc = acc * dis[node] + bias[lane];
  Hout[(size_t)node * 64 + lane] = (acc > 0.f) ? acc : SLOPE * acc;
}

// One wave per graph: mean-pool + fc1 + lrelu + fc2
__launch_bounds__(64)
__global__ void k_pool(const float* __restrict__ H, const int* __restrict__ batch,
                       const float* __restrict__ f1W, const float* __restrict__ f1b,
                       const float* __restrict__ f2W, const float* __restrict__ f2b,
                       float* __restrict__ out, int N) {
  int g = blockIdx.x;
  int lane = threadIdx.x;
  int lo = 0, hi = N;
  while (lo < hi) { int m = (lo + hi) >> 1; if (batch[m] < g) lo = m + 1; else hi = m; }
  int beg = lo;
  hi = N;
  while (lo < hi) { int m = (lo + hi) >> 1; if (batch[m] < g + 1) lo = m + 1; else hi = m; }
  int end = lo;
  float acc = 0.f;
  for (int r = beg; r < end; ++r) acc += H[(size_t)r * 64 + lane];
  float c = (float)(end - beg);
  acc /= (c < 1.f ? 1.f : c);
  __shared__ float p[64];
  p[lane] = acc;
  __syncthreads();
  float q = f1b[lane];
  #pragma unroll
  for (int k = 0; k < 64; ++k) q += p[k] * f1W[k * 64 + lane];
  q = (q > 0.f) ? q : SLOPE * q;
  float v = q * f2W[lane];
  #pragma unroll
  for (int off = 32; off > 0; off >>= 1) v += __shfl_down(v, off, 64);
  if (lane == 0) out[g] = v + f2b[0];
}

extern "C" void kernel_launch(void* const* d_in, const int* in_sizes, int n_in,
                              void* d_out, int out_size, void* d_ws, size_t ws_size,
                              hipStream_t stream) {
  const float* x    = (const float*)d_in[0];
  const int*  eidx  = (const int*)d_in[1];
  const int*  batch = (const int*)d_in[2];
  const float* W0 = (const float*)d_in[3];
  const float* b0 = (const float*)d_in[4];
  const float* W1 = (const float*)d_in[5];
  const float* b1 = (const float*)d_in[6];
  const float* W2 = (const float*)d_in[7];
  const float* b2 = (const float*)d_in[8];
  const float* f1W = (const float*)d_in[9];
  const float* f1b = (const float*)d_in[10];
  const float* f2W = (const float*)d_in[11];
  const float* f2b = (const float*)d_in[12];
  float* out = (float*)d_out;

  const int N = NN, E = NE;
  const int* src  = eidx;
  const int* dstp = eidx + E;

  const size_t NPAD = 100096;   // 782*128 rows exactly
  char* w = (char*)d_ws;
  float* bufA  = (float*)w; w += NPAD * 64 * 4;   // bedge aliases bufA (dead until gemm0)
  float* bufB  = (float*)w; w += NPAD * 64 * 4;
  int*   csr   = (int*)w;   w += (size_t)E * 4;
  int*   offs  = (int*)w;   w += (size_t)(N + 4) * 4;
  float* dis   = (float*)w; w += (size_t)N * 4;
  int*   bh    = (int*)w;   w += (size_t)NBLK * NBUK * 4;
  int*   btot  = (int*)w;   w += (NBUK + 1) * 4;
  int*   boffs = (int*)w;   w += (NBUK + 4) * 4;
  short* wt0h  = (short*)w; w += 64 * 192 * 2;
  short* wt0l  = (short*)w; w += 64 * 192 * 2;
  short* wt1h  = (short*)w; w += 64 * 64 * 2;
  short* wt1l  = (short*)w; w += 64 * 64 * 2;
  short* wt2h  = (short*)w; w += 64 * 64 * 2;
  short* wt2l  = (short*)w; w += 64 * 64 * 2;
  unsigned* bedge = (unsigned*)bufA;

  k_wsplit<<<48, 256, 0, stream>>>(W0, wt0h, wt0l, NODE_IN, 192);
  k_wsplit<<<16, 256, 0, stream>>>(W1, wt1h, wt1l, 64, 64);
  k_wsplit<<<16, 256, 0, stream>>>(W2, wt2h, wt2l, 64, 64);

  k_hist<<<NBLK, 256, 0, stream>>>(dstp, bh, E);
  k_bucket_scan<<<NBUK, 256, 0, stream>>>(bh, btot);
  k_btot_scan<<<1, 512, 0, stream>>>(btot, boffs, E);
  k_scatter<<<NBLK, 256, 0, stream>>>(src, dstp, bh, boffs, bedge, E);
  k_b2csr<<<NBUK, 256, 0, stream>>>(bedge, boffs, offs, dis, csr, N);

  const int NTB = (N + 127) / 128;   // 782
  k_gemm<NODE_IN, 192><<<NTB, 256, 0, stream>>>(x, wt0h, wt0l, dis, bufA, N);
  k_agg<<<(N + 3) / 4, 256, 0, stream>>>(bufA, offs, csr, dis, b0, bufB, N);
  k_gemm<64, 64><<<NTB, 256, 0, stream>>>(bufB, wt1h, wt1l, dis, bufA, N);
  k_agg<<<(N + 3) / 4, 256, 0, stream>>>(bufA, offs, csr, dis, b1, bufB, N);
  k_gemm<64, 64><<<NTB, 256, 0, stream>>>(bufB, wt2h, wt2l, dis, bufA, N);
  k_agg<<<(N + 3) / 4, 256, 0, stream>>>(bufA, offs, csr, dis, b2, bufB, N);
  k_pool<<<NG, 64, 0, stream>>>(bufB, batch, f1W, f1b, f2W, f2b, out, N);
}

// Round 14
// 322.904 us; speedup vs baseline: 1.4249x; 1.0878x over previous
//
#include <hip/hip_runtime.h>

#define NN 100000
#define NE 1600000
#define NG 1024
#define NODE_IN 163
#define SLOPE 0.01f
#define NBUK 391
#define BUKSH 8
#define EPB 8192
#define NBLK ((NE + EPB - 1) / EPB)

typedef short s16x8 __attribute__((ext_vector_type(8)));
typedef float f32x4 __attribute__((ext_vector_type(4)));

__device__ __forceinline__ unsigned short bf16_rne(float x) {
  unsigned u = __float_as_uint(x);
  return (unsigned short)((u + 0x7FFFu + ((u >> 16) & 1u)) >> 16);
}
__device__ __forceinline__ float bf16_f32(unsigned short h) {
  return __uint_as_float(((unsigned)h) << 16);
}

// ---------------- CSR build (privatized counting sort; round-4, verified) -------------
__global__ void k_hist(const int* __restrict__ dst, int* __restrict__ bh, int E) {
  __shared__ int h[NBUK];
  for (int i = threadIdx.x; i < NBUK; i += 256) h[i] = 0;
  __syncthreads();
  int beg = blockIdx.x * EPB, end = min(E, beg + EPB);
  for (int e = beg + threadIdx.x; e < end; e += 256) atomicAdd(&h[dst[e] >> BUKSH], 1);
  __syncthreads();
  for (int i = threadIdx.x; i < NBUK; i += 256) bh[blockIdx.x * NBUK + i] = h[i];
}

__global__ void k_bucket_scan(int* __restrict__ bh, int* __restrict__ btot) {
  __shared__ int s[256];
  int bucket = blockIdx.x, tid = threadIdx.x;
  int v = (tid < NBLK) ? bh[tid * NBUK + bucket] : 0;
  s[tid] = v;
  __syncthreads();
  for (int off = 1; off < 256; off <<= 1) {
    int t = (tid >= off) ? s[tid - off] : 0;
    __syncthreads();
    s[tid] += t;
    __syncthreads();
  }
  if (tid < NBLK) bh[tid * NBUK + bucket] = s[tid] - v;
  if (tid == 255) btot[bucket] = s[255];
}

__global__ void k_btot_scan(const int* __restrict__ btot, int* __restrict__ boffs, int E) {
  __shared__ int s[512];
  int tid = threadIdx.x;
  int v = (tid < NBUK) ? btot[tid] : 0;
  s[tid] = v;
  __syncthreads();
  for (int off = 1; off < 512; off <<= 1) {
    int t = (tid >= off) ? s[tid - off] : 0;
    __syncthreads();
    s[tid] += t;
    __syncthreads();
  }
  if (tid < NBUK) boffs[tid] = s[tid] - v;
  if (tid == 0) boffs[NBUK] = E;
}

__global__ void k_scatter(const int* __restrict__ src, const int* __restrict__ dst,
                          const int* __restrict__ bh, const int* __restrict__ boffs,
                          unsigned* __restrict__ bedge, int E) {
  __shared__ int cur[NBUK];
  for (int i = threadIdx.x; i < NBUK; i += 256)
    cur[i] = boffs[i] + bh[blockIdx.x * NBUK + i];
  __syncthreads();
  int beg = blockIdx.x * EPB, end = min(E, beg + EPB);
  for (int e = beg + threadIdx.x; e < end; e += 256) {
    int d = dst[e];
    int pos = atomicAdd(&cur[d >> BUKSH], 1);
    bedge[pos] = (unsigned)src[e] | ((unsigned)(d & 255) << 17);
  }
}

__global__ void k_b2csr(const unsigned* __restrict__ bedge, const int* __restrict__ boffs,
                        int* __restrict__ offs, float* __restrict__ dis,
                        int* __restrict__ csr, int N) {
  __shared__ int lcnt[256];
  __shared__ int s[256];
  __shared__ int lcur[256];
  int b = blockIdx.x, tid = threadIdx.x;
  int beg = boffs[b], end = boffs[b + 1];
  lcnt[tid] = 0;
  __syncthreads();
  for (int e = beg + tid; e < end; e += 256) atomicAdd(&lcnt[bedge[e] >> 17], 1);
  __syncthreads();
  int v = lcnt[tid];
  s[tid] = v;
  __syncthreads();
  for (int off = 1; off < 256; off <<= 1) {
    int t = (tid >= off) ? s[tid - off] : 0;
    __syncthreads();
    s[tid] += t;
    __syncthreads();
  }
  int o = s[tid] - v;
  int node = (b << BUKSH) + tid;
  if (node <= N) offs[node] = beg + o;
  if (node < N) dis[node] = rsqrtf((float)(v + 1));
  lcur[tid] = o;
  __syncthreads();
  for (int e = beg + tid; e < end; e += 256) {
    unsigned w = bedge[e];
    int p = atomicAdd(&lcur[w >> 17], 1);
    csr[beg + p] = (int)(w & 0x1FFFFu);
  }
}

// ---------------- W pre-split: W[K][64] fp32 -> Wt_hi/lo[64][KP] bf16 (transposed) ----
__global__ void k_wsplit(const float* __restrict__ W, short* __restrict__ hi,
                         short* __restrict__ lo, int K, int KP) {
  int idx = blockIdx.x * 256 + threadIdx.x;
  if (idx >= 64 * KP) return;
  int c = idx / KP, kk = idx - c * KP;
  float v = (kk < K) ? W[(size_t)kk * 64 + c] : 0.f;
  unsigned short h = bf16_rne(v);
  hi[idx] = (short)h;
  lo[idx] = (short)bf16_rne(v - bf16_f32(h));
}

// ---------------- GEMM via MFMA split-bf16; output bf16 rows (consumed by agg) --------
template<int K, int KP>
__launch_bounds__(256)
__global__ void k_gemm(const float* __restrict__ X, const short* __restrict__ Whi,
                       const short* __restrict__ Wlo, const float* __restrict__ disv,
                       unsigned short* __restrict__ Y, int N) {
  constexpr int KC = KP / 32;
  constexpr int PA = 40;
  constexpr int PB = 40;
  __shared__ __align__(16) short sAh[2][128 * PA];
  __shared__ __align__(16) short sAl[2][128 * PA];
  __shared__ __align__(16) short sBh[2][64 * PB];
  __shared__ __align__(16) short sBl[2][64 * PB];

  const int tid = threadIdx.x;
  const int lane = tid & 63, wv = tid >> 6;
  const int l15 = lane & 15, l4 = lane >> 4;
  const int gbase = blockIdx.x << 7;

  const int arow = tid >> 1, akh = (tid & 1) << 4;
  int grow = gbase + arow;
  if (K != KP) grow = min(grow, N - 1);
  const float* xr = X + (size_t)grow * K;
  const int bcol = tid >> 2, bk8 = (tid & 3) << 3;

  float4 ra0, ra1, ra2, ra3;
  s16x8 rbh, rbl;

  auto loadA = [&](int c) {
    if (K != KP && c == KC - 1) {
      ra0 = ra1 = ra2 = ra3 = make_float4(0.f, 0.f, 0.f, 0.f);
      if (akh == 0) { ra0.x = xr[160]; ra0.y = xr[161]; ra0.z = xr[162]; }
    } else {
      const float* p = xr + c * 32 + akh;
      ra0 = *(const float4*)(p);
      ra1 = *(const float4*)(p + 4);
      ra2 = *(const float4*)(p + 8);
      ra3 = *(const float4*)(p + 12);
    }
  };
  auto loadB = [&](int c) {
    const size_t o = (size_t)bcol * KP + c * 32 + bk8;
    rbh = *(const s16x8*)(Whi + o);
    rbl = *(const s16x8*)(Wlo + o);
  };
  auto writeLDS = [&](int b) {
    short hb[16], lb[16];
    float v[16] = {ra0.x, ra0.y, ra0.z, ra0.w, ra1.x, ra1.y, ra1.z, ra1.w,
                   ra2.x, ra2.y, ra2.z, ra2.w, ra3.x, ra3.y, ra3.z, ra3.w};
    #pragma unroll
    for (int j = 0; j < 16; ++j) {
      unsigned short h = bf16_rne(v[j]);
      hb[j] = (short)h;
      lb[j] = (short)bf16_rne(v[j] - bf16_f32(h));
    }
    short* ah = sAh[b] + arow * PA + akh;
    *(s16x8*)(ah) = *(const s16x8*)(hb);
    *(s16x8*)(ah + 8) = *(const s16x8*)(hb + 8);
    short* al = sAl[b] + arow * PA + akh;
    *(s16x8*)(al) = *(const s16x8*)(lb);
    *(s16x8*)(al + 8) = *(const s16x8*)(lb + 8);
    *(s16x8*)(sBh[b] + bcol * PB + bk8) = rbh;
    *(s16x8*)(sBl[b] + bcol * PB + bk8) = rbl;
  };

  f32x4 acc[2][4];
  #pragma unroll
  for (int rt = 0; rt < 2; ++rt)
    #pragma unroll
    for (int ct = 0; ct < 4; ++ct) acc[rt][ct] = (f32x4){0.f, 0.f, 0.f, 0.f};

  loadA(0); loadB(0); writeLDS(0);
  __syncthreads();

  #pragma unroll 1
  for (int c = 0; c < KC; ++c) {
    if (c + 1 < KC) { loadA(c + 1); loadB(c + 1); }   // issue early (T14)
    const int b = c & 1;
    const int aoff0 = (wv * 32 + l15) * PA + l4 * 8;
    const int aoff1 = aoff0 + 16 * PA;
    s16x8 a0h = *(const s16x8*)(sAh[b] + aoff0);
    s16x8 a0l = *(const s16x8*)(sAl[b] + aoff0);
    s16x8 a1h = *(const s16x8*)(sAh[b] + aoff1);
    s16x8 a1l = *(const s16x8*)(sAl[b] + aoff1);
    #pragma unroll
    for (int ct = 0; ct < 4; ++ct) {
      const int boff = (ct * 16 + l15) * PB + l4 * 8;
      s16x8 bh = *(const s16x8*)(sBh[b] + boff);
      s16x8 bl = *(const s16x8*)(sBl[b] + boff);
      acc[0][ct] = __builtin_amdgcn_mfma_f32_16x16x32_bf16(a0h, bh, acc[0][ct], 0, 0, 0);
      acc[0][ct] = __builtin_amdgcn_mfma_f32_16x16x32_bf16(a0l, bh, acc[0][ct], 0, 0, 0);
      acc[0][ct] = __builtin_amdgcn_mfma_f32_16x16x32_bf16(a0h, bl, acc[0][ct], 0, 0, 0);
      acc[1][ct] = __builtin_amdgcn_mfma_f32_16x16x32_bf16(a1h, bh, acc[1][ct], 0, 0, 0);
      acc[1][ct] = __builtin_amdgcn_mfma_f32_16x16x32_bf16(a1l, bh, acc[1][ct], 0, 0, 0);
      acc[1][ct] = __builtin_amdgcn_mfma_f32_16x16x32_bf16(a1h, bl, acc[1][ct], 0, 0, 0);
    }
    if (c + 1 < KC) { writeLDS((c + 1) & 1); __syncthreads(); }
  }

  const int rb = gbase + wv * 32;
  #pragma unroll
  for (int rt = 0; rt < 2; ++rt) {
    #pragma unroll
    for (int j = 0; j < 4; ++j) {
      int row = rb + rt * 16 + l4 * 4 + j;
      if (row < N) {
        float d = disv[row];
        unsigned short* yp = Y + ((size_t)row << 6) + l15;
        yp[0]  = bf16_rne(acc[rt][0][j] * d);
        yp[16] = bf16_rne(acc[rt][1][j] * d);
        yp[32] = bf16_rne(acc[rt][2][j] * d);
        yp[48] = bf16_rne(acc[rt][3][j] * d);
      }
    }
  }
}

// One wave per node; gathers bf16 rows (half the HBM/L3 traffic), fp32 accumulate.
__launch_bounds__(256)
__global__ void k_agg(const unsigned short* __restrict__ G, const int* __restrict__ offs,
                      const int* __restrict__ csr, const float* __restrict__ dis,
                      const float* __restrict__ bias, float* __restrict__ H, int N) {
  int node = blockIdx.x * 4 + (threadIdx.x >> 6);
  if (node >= N) return;
  int lane = threadIdx.x & 63;
  const unsigned short* Gl = G + lane;
  int beg = offs[node], end = offs[node + 1];
  float acc = bf16_f32(Gl[(size_t)node << 6]);
  int e = beg;
  for (; e + 16 <= end; e += 16) {
    int s[16];
    #pragma unroll
    for (int j = 0; j < 16; ++j) s[j] = csr[e + j];
    #pragma unroll
    for (int j = 0; j < 16; ++j) acc += bf16_f32(Gl[(size_t)s[j] << 6]);
  }
  for (; e + 4 <= end; e += 4) {
    int s0 = csr[e], s1 = csr[e + 1], s2 = csr[e + 2], s3 = csr[e + 3];
    acc += bf16_f32(Gl[(size_t)s0 << 6]);
    acc += bf16_f32(Gl[(size_t)s1 << 6]);
    acc += bf16_f32(Gl[(size_t)s2 << 6]);
    acc += bf16_f32(Gl[(size_t)s3 << 6]);
  }
  for (; e < end; ++e) acc += bf16_f32(Gl[(size_t)csr[e] << 6]);
  acc = acc * dis[node] + bias[lane];
  H[((size_t)node << 6) + lane] = (acc > 0.f) ? acc : SLOPE * acc;
}

// One wave per graph: mean-pool + fc1 + lrelu + fc2
__launch_bounds__(64)
__global__ void k_pool(const float* __restrict__ H, const int* __restrict__ batch,
                       const float* __restrict__ f1W, const float* __restrict__ f1b,
                       const float* __restrict__ f2W, const float* __restrict__ f2b,
                       float* __restrict__ out, int N) {
  int g = blockIdx.x;
  int lane = threadIdx.x;
  int lo = 0, hi = N;
  while (lo < hi) { int m = (lo + hi) >> 1; if (batch[m] < g) lo = m + 1; else hi = m; }
  int beg = lo;
  hi = N;
  while (lo < hi) { int m = (lo + hi) >> 1; if (batch[m] < g + 1) lo = m + 1; else hi = m; }
  int end = lo;
  float acc = 0.f;
  for (int r = beg; r < end; ++r) acc += H[(size_t)r * 64 + lane];
  float c = (float)(end - beg);
  acc /= (c < 1.f ? 1.f : c);
  __shared__ float p[64];
  p[lane] = acc;
  __syncthreads();
  float q = f1b[lane];
  #pragma unroll
  for (int k = 0; k < 64; ++k) q += p[k] * f1W[k * 64 + lane];
  q = (q > 0.f) ? q : SLOPE * q;
  float v = q * f2W[lane];
  #pragma unroll
  for (int off = 32; off > 0; off >>= 1) v += __shfl_down(v, off, 64);
  if (lane == 0) out[g] = v + f2b[0];
}

extern "C" void kernel_launch(void* const* d_in, const int* in_sizes, int n_in,
                              void* d_out, int out_size, void* d_ws, size_t ws_size,
                              hipStream_t stream) {
  const float* x    = (const float*)d_in[0];
  const int*  eidx  = (const int*)d_in[1];
  const int*  batch = (const int*)d_in[2];
  const float* W0 = (const float*)d_in[3];
  const float* b0 = (const float*)d_in[4];
  const float* W1 = (const float*)d_in[5];
  const float* b1 = (const float*)d_in[6];
  const float* W2 = (const float*)d_in[7];
  const float* b2 = (const float*)d_in[8];
  const float* f1W = (const float*)d_in[9];
  const float* f1b = (const float*)d_in[10];
  const float* f2W = (const float*)d_in[11];
  const float* f2b = (const float*)d_in[12];
  float* out = (float*)d_out;

  const int N = NN, E = NE;
  const int* src  = eidx;
  const int* dstp = eidx + E;

  const size_t NPAD = 100096;   // 782*128 rows exactly
  char* w = (char*)d_ws;
  float* H     = (float*)w; w += NPAD * 64 * 4;        // fp32 layer buffer (aliases bedge)
  unsigned short* G = (unsigned short*)w; w += NPAD * 64 * 2;  // bf16 gemm output
  int*   csr   = (int*)w;   w += (size_t)E * 4;
  int*   offs  = (int*)w;   w += (size_t)(N + 4) * 4;
  float* dis   = (float*)w; w += (size_t)N * 4;
  int*   bh    = (int*)w;   w += (size_t)NBLK * NBUK * 4;
  int*   btot  = (int*)w;   w += (NBUK + 1) * 4;
  int*   boffs = (int*)w;   w += (NBUK + 4) * 4;
  short* wt0h  = (short*)w; w += 64 * 192 * 2;
  short* wt0l  = (short*)w; w += 64 * 192 * 2;
  short* wt1h  = (short*)w; w += 64 * 64 * 2;
  short* wt1l  = (short*)w; w += 64 * 64 * 2;
  short* wt2h  = (short*)w; w += 64 * 64 * 2;
  short* wt2l  = (short*)w; w += 64 * 64 * 2;
  unsigned* bedge = (unsigned*)H;

  k_wsplit<<<48, 256, 0, stream>>>(W0, wt0h, wt0l, NODE_IN, 192);
  k_wsplit<<<16, 256, 0, stream>>>(W1, wt1h, wt1l, 64, 64);
  k_wsplit<<<16, 256, 0, stream>>>(W2, wt2h, wt2l, 64, 64);

  k_hist<<<NBLK, 256, 0, stream>>>(dstp, bh, E);
  k_bucket_scan<<<NBUK, 256, 0, stream>>>(bh, btot);
  k_btot_scan<<<1, 512, 0, stream>>>(btot, boffs, E);
  k_scatter<<<NBLK, 256, 0, stream>>>(src, dstp, bh, boffs, bedge, E);
  k_b2csr<<<NBUK, 256, 0, stream>>>(bedge, boffs, offs, dis, csr, N);

  const int NTB = (N + 127) / 128;   // 782
  k_gemm<NODE_IN, 192><<<NTB, 256, 0, stream>>>(x, wt0h, wt0l, dis, G, N);
  k_agg<<<(N + 3) / 4, 256, 0, stream>>>(G, offs, csr, dis, b0, H, N);
  k_gemm<64, 64><<<NTB, 256, 0, stream>>>(H, wt1h, wt1l, dis, G, N);
  k_agg<<<(N + 3) / 4, 256, 0, stream>>>(G, offs, csr, dis, b1, H, N);
  k_gemm<64, 64><<<NTB, 256, 0, stream>>>(H, wt2h, wt2l, dis, G, N);
  k_agg<<<(N + 3) / 4, 256, 0, stream>>>(G, offs, csr, dis, b2, H, N);
  k_pool<<<NG, 64, 0, stream>>>(H, batch, f1W, f1b, f2W, f2b, out, N);
}